// Round 1
// baseline (5318.055 us; speedup 1.0000x reference)
//
#include <hip/hip_runtime.h>
#include <hip/hip_bf16.h>

#define NCn 2000
#define NOn 100000
#define NEn 200000
#define Dn  128
#define ECOn 100000
#define EOCn 100000
#define EEOn 200000
#define EOEn 200000

// ---------------- degree counting ----------------
__global__ __launch_bounds__(256) void deg_count(const int* __restrict__ src,
                                                 const int* __restrict__ dst,
                                                 int n, float* __restrict__ dout,
                                                 float* __restrict__ din) {
  int i = blockIdx.x * 256 + threadIdx.x;
  if (i < n) {
    atomicAdd(&dout[src[i]], 1.0f);
    atomicAdd(&din[dst[i]], 1.0f);
  }
}

__global__ __launch_bounds__(256) void deg_fin(float* __restrict__ d, int n) {
  int i = blockIdx.x * 256 + threadIdx.x;
  if (i < n) d[i] = rsqrtf(fmaxf(d[i], 1.0f));
}

// ---------------- xs = (X * inv_out[:,None]) @ W ----------------
// 32 rows/block, 256 threads. W staged in LDS in two 64-row chunks.
// Thread computes 16 cols: c0+{0..3}, c0+32+{0..3}, c0+64+{0..3}, c0+96+{0..3}
// (c0 = (tid&7)*4) so each ds_read_b128 instruction covers all 32 banks.
__global__ __launch_bounds__(256) void gemm_xs(const float* __restrict__ X,
                                               const float* __restrict__ W,
                                               const float* __restrict__ inv_out,
                                               float* __restrict__ XS, int n) {
  __shared__ float wl[64 * 128];
  __shared__ float xl[32 * 128];
  int tid = threadIdx.x;
  int base = blockIdx.x * 32;
  for (int i = tid * 4; i < 32 * 128; i += 1024) {
    int node = i >> 7, c = i & 127;
    int r = base + node;
    float4 v = make_float4(0.f, 0.f, 0.f, 0.f);
    if (r < n) v = *(const float4*)&X[(size_t)r * 128 + c];
    *(float4*)&xl[i] = v;
  }
  float acc[16];
#pragma unroll
  for (int m = 0; m < 16; ++m) acc[m] = 0.f;
  int r = tid >> 3;
  int c0 = (tid & 7) * 4;
  for (int chunk = 0; chunk < 2; ++chunk) {
    __syncthreads();
    for (int i = tid * 4; i < 64 * 128; i += 1024)
      *(float4*)&wl[i] = *(const float4*)&W[chunk * 64 * 128 + i];
    __syncthreads();
    const float* xr = &xl[r * 128 + chunk * 64];
#pragma unroll 4
    for (int k = 0; k < 64; ++k) {
      float a = xr[k];
      const float* wr = &wl[k * 128];
#pragma unroll
      for (int g = 0; g < 4; ++g) {
        float4 w4 = *(const float4*)&wr[c0 + 32 * g];
        acc[g * 4 + 0] = fmaf(a, w4.x, acc[g * 4 + 0]);
        acc[g * 4 + 1] = fmaf(a, w4.y, acc[g * 4 + 1]);
        acc[g * 4 + 2] = fmaf(a, w4.z, acc[g * 4 + 2]);
        acc[g * 4 + 3] = fmaf(a, w4.w, acc[g * 4 + 3]);
      }
    }
  }
  int row = base + r;
  if (row < n) {
    float s = inv_out[row];
#pragma unroll
    for (int g = 0; g < 4; ++g) {
      float4 v = make_float4(acc[g * 4 + 0] * s, acc[g * 4 + 1] * s,
                             acc[g * 4 + 2] * s, acc[g * 4 + 3] * s);
      *(float4*)&XS[(size_t)row * 128 + c0 + 32 * g] = v;
    }
  }
}

// ---------------- scatter: SP[dst] += XS[src] * inv_in[dst] ----------------
__global__ __launch_bounds__(256) void scatter_add(const float* __restrict__ XS,
                                                   const int* __restrict__ src,
                                                   const int* __restrict__ dst,
                                                   const float* __restrict__ inv_in,
                                                   float* __restrict__ SP, int n) {
  int t = blockIdx.x * 256 + threadIdx.x;
  int e = t >> 4;
  if (e >= n) return;
  int sg = t & 15;
  int s = src[e], d = dst[e];
  float w = inv_in[d];
  const float* xr = &XS[(size_t)s * 128 + sg * 8];
  float* op = &SP[(size_t)d * 128 + sg * 8];
  float4 v0 = *(const float4*)xr;
  float4 v1 = *(const float4*)(xr + 4);
  atomicAdd(op + 0, v0.x * w);
  atomicAdd(op + 1, v0.y * w);
  atomicAdd(op + 2, v0.z * w);
  atomicAdd(op + 3, v0.w * w);
  atomicAdd(op + 4, v1.x * w);
  atomicAdd(op + 5, v1.y * w);
  atomicAdd(op + 6, v1.z * w);
  atomicAdd(op + 7, v1.w * w);
}

// ---------------- fuse + GRU ----------------
// 32 nodes/block, 256 threads = 128 j-cols x 2 node-halves (16 nodes each).
// cat[node][0:128]=sp+bias, [128:256]=h1, [256:384]=h2. All LDS reads are
// wave-uniform (broadcast). Weight rows stream per-lane through L1/L2.
#define GRU_DOTS(ROWOFF, AI, AH)                                              \
  {                                                                           \
    float bi_ = bih[(ROWOFF) + j], bh_ = bhh[(ROWOFF) + j];                   \
    _Pragma("unroll") for (int m = 0; m < 16; ++m) { AI[m] = bi_; AH[m] = bh_; } \
    const float* wi_ = &WIH[(size_t)((ROWOFF) + j) * 128];                    \
    const float* wh_ = &WHH[(size_t)((ROWOFF) + j) * 128];                    \
    for (int k = 0; k < 128; k += 4) {                                        \
      float4 a_ = *(const float4*)&wi_[k];                                    \
      float4 b_ = *(const float4*)&wh_[k];                                    \
      _Pragma("unroll") for (int m = 0; m < 16; ++m) {                        \
        int node_ = nb0 + m;                                                  \
        float4 x_ = *(const float4*)&cat[node_ * 384 + k];                    \
        float4 f_ = *(const float4*)&fus[node_ * 128 + k];                    \
        AI[m] = fmaf(x_.x, a_.x, fmaf(x_.y, a_.y, fmaf(x_.z, a_.z, fmaf(x_.w, a_.w, AI[m])))); \
        AH[m] = fmaf(f_.x, b_.x, fmaf(f_.y, b_.y, fmaf(f_.z, b_.z, fmaf(f_.w, b_.w, AH[m])))); \
      }                                                                       \
    }                                                                         \
  }

__global__ __launch_bounds__(256) void fuse_update(
    const float* __restrict__ SP, const float* __restrict__ H1,
    const float* __restrict__ H2, const float* __restrict__ bA,
    const float* __restrict__ bB, const float* __restrict__ GW,
    const float* __restrict__ gb, const float* __restrict__ WIH,
    const float* __restrict__ WHH, const float* __restrict__ bih,
    const float* __restrict__ bhh, float* __restrict__ OUT,
    float* __restrict__ GOUT, int n) {
  __shared__ float cat[32 * 384];
  __shared__ float fus[32 * 128];
  int tid = threadIdx.x;
  int base = blockIdx.x * 32;

  for (int i = tid * 4; i < 32 * 128; i += 1024) {
    int node = i >> 7, c = i & 127;
    int r = base + node;
    float4 v = make_float4(0.f, 0.f, 0.f, 0.f);
    float4 v1 = v, v2 = v;
    if (r < n) {
      v = *(const float4*)&SP[(size_t)r * 128 + c];
      float4 b1 = *(const float4*)&bA[c];
      v.x += b1.x; v.y += b1.y; v.z += b1.z; v.w += b1.w;
      if (bB) {
        float4 b2 = *(const float4*)&bB[c];
        v.x += b2.x; v.y += b2.y; v.z += b2.z; v.w += b2.w;
      }
      v1 = *(const float4*)&H1[(size_t)r * 128 + c];
      v2 = *(const float4*)&H2[(size_t)r * 128 + c];
    }
    *(float4*)&cat[node * 384 + c] = v;
    *(float4*)&cat[node * 384 + 128 + c] = v1;
    *(float4*)&cat[node * 384 + 256 + c] = v2;
  }
  __syncthreads();

  int j = tid & 127, half = tid >> 7;
  int nb0 = half * 16;

  // ---- gate = sigmoid(cat @ gate_W.T + gate_b) ----
  float acc[16];
  {
    float b0 = gb[j];
#pragma unroll
    for (int m = 0; m < 16; ++m) acc[m] = b0;
    const float* gw = &GW[(size_t)j * 384];
    for (int k = 0; k < 384; k += 4) {
      float4 w = *(const float4*)&gw[k];
#pragma unroll
      for (int m = 0; m < 16; ++m) {
        float4 x = *(const float4*)&cat[(nb0 + m) * 384 + k];
        acc[m] = fmaf(x.x, w.x, fmaf(x.y, w.y, fmaf(x.z, w.z, fmaf(x.w, w.w, acc[m]))));
      }
    }
  }
#pragma unroll
  for (int m = 0; m < 16; ++m) {
    float g = 1.f / (1.f + __expf(-acc[m]));
    int node = nb0 + m;
    float h1v = cat[node * 384 + 128 + j];
    float h2v = cat[node * 384 + 256 + j];
    float f = fmaf(g, h1v - h2v, h2v);  // g*h1 + (1-g)*h2
    fus[node * 128 + j] = f;
    int r = base + node;
    if (r < n) GOUT[(size_t)r * 128 + j] = g;
  }
  __syncthreads();

  // ---- GRU ----
  float ai[16], ah[16], rr[16], zz[16];
  GRU_DOTS(0, ai, ah);
#pragma unroll
  for (int m = 0; m < 16; ++m) rr[m] = 1.f / (1.f + __expf(-(ai[m] + ah[m])));
  GRU_DOTS(128, ai, ah);
#pragma unroll
  for (int m = 0; m < 16; ++m) zz[m] = 1.f / (1.f + __expf(-(ai[m] + ah[m])));
  GRU_DOTS(256, ai, ah);
#pragma unroll
  for (int m = 0; m < 16; ++m) {
    float x = ai[m] + rr[m] * ah[m];
    x = fminf(fmaxf(x, -15.f), 15.f);
    float e = __expf(2.f * x);
    float nv = (e - 1.f) / (e + 1.f);  // tanh
    int node = nb0 + m;
    float f = fus[node * 128 + j];
    float ht = fmaf(zz[m], f - nv, nv);  // (1-z)*n + z*fused
    ht = fmaxf(ht, 0.f);
    int r = base + node;
    if (r < n) OUT[(size_t)r * 128 + j] = ht;
  }
}

extern "C" void kernel_launch(void* const* d_in, const int* in_sizes, int n_in,
                              void* d_out, int out_size, void* d_ws, size_t ws_size,
                              hipStream_t stream) {
  const float* h_course = (const float*)d_in[0];
  const float* h_object = (const float*)d_in[1];
  const float* h_enroll = (const float*)d_in[2];
  const float* h1_course = (const float*)d_in[3];
  const float* h1_object = (const float*)d_in[4];
  const float* h1_enroll = (const float*)d_in[5];
  const float* h2_course = (const float*)d_in[6];
  const float* h2_object = (const float*)d_in[7];
  const float* h2_enroll = (const float*)d_in[8];
  const int* src_co = (const int*)d_in[9];
  const int* dst_co = (const int*)d_in[10];
  const int* src_oc = (const int*)d_in[11];
  const int* dst_oc = (const int*)d_in[12];
  const int* src_eo = (const int*)d_in[13];
  const int* dst_eo = (const int*)d_in[14];
  const int* src_oe = (const int*)d_in[15];
  const int* dst_oe = (const int*)d_in[16];
  const float* W_co = (const float*)d_in[17];
  const float* b_co = (const float*)d_in[18];
  const float* W_oc = (const float*)d_in[19];
  const float* b_oc = (const float*)d_in[20];
  const float* W_eo = (const float*)d_in[21];
  const float* b_eo = (const float*)d_in[22];
  const float* W_oe = (const float*)d_in[23];
  const float* b_oe = (const float*)d_in[24];
  const float* gate_W = (const float*)d_in[25];
  const float* gate_b = (const float*)d_in[26];
  const float* W_ih = (const float*)d_in[27];
  const float* W_hh = (const float*)d_in[28];
  const float* b_ih = (const float*)d_in[29];
  const float* b_hh = (const float*)d_in[30];

  float* out = (float*)d_out;
  // output regions
  float* out_c = out;                          // NC*D
  float* out_o = out + (size_t)NCn * Dn;       // NO*D
  float* out_e = out + (size_t)(NCn + NOn) * Dn;
  float* g_c = out + (size_t)(NCn + NOn + NEn) * Dn;  // gate region doubles as sp accumulators
  float* g_o = g_c + (size_t)NCn * Dn;
  float* g_e = g_o + (size_t)NOn * Dn;

  // scratch inside the out_c/out_o/out_e region (dead until fuse writes it)
  float* xs = out;                              // NE*D floats max
  float* deg = out + (size_t)NEn * Dn;          // 804000 floats
  float* inv_out_co = deg;                      // NC
  float* inv_in_co = deg + 2000;                // NO
  float* inv_out_oc = deg + 102000;             // NO
  float* inv_in_oc = deg + 202000;              // NC
  float* inv_out_eo = deg + 204000;             // NE
  float* inv_in_eo = deg + 404000;              // NO
  float* inv_out_oe = deg + 504000;             // NO
  float* inv_in_oe = deg + 604000;              // NE

  // zero degree tables and sp accumulators (gate region)
  hipMemsetAsync(deg, 0, 804000 * sizeof(float), stream);
  hipMemsetAsync(g_c, 0, (size_t)(NCn + NOn + NEn) * Dn * sizeof(float), stream);

  deg_count<<<(ECOn + 255) / 256, 256, 0, stream>>>(src_co, dst_co, ECOn, inv_out_co, inv_in_co);
  deg_count<<<(EOCn + 255) / 256, 256, 0, stream>>>(src_oc, dst_oc, EOCn, inv_out_oc, inv_in_oc);
  deg_count<<<(EEOn + 255) / 256, 256, 0, stream>>>(src_eo, dst_eo, EEOn, inv_out_eo, inv_in_eo);
  deg_count<<<(EOEn + 255) / 256, 256, 0, stream>>>(src_oe, dst_oe, EOEn, inv_out_oe, inv_in_oe);
  deg_fin<<<(804000 + 255) / 256, 256, 0, stream>>>(deg, 804000);

  // relation co: course -> object
  gemm_xs<<<(NCn + 31) / 32, 256, 0, stream>>>(h_course, W_co, inv_out_co, xs, NCn);
  scatter_add<<<(ECOn * 16 + 255) / 256, 256, 0, stream>>>(xs, src_co, dst_co, inv_in_co, g_o, ECOn);
  // relation eo: enrollment -> object
  gemm_xs<<<(NEn + 31) / 32, 256, 0, stream>>>(h_enroll, W_eo, inv_out_eo, xs, NEn);
  scatter_add<<<(EEOn * 16 + 255) / 256, 256, 0, stream>>>(xs, src_eo, dst_eo, inv_in_eo, g_o, EEOn);
  // relation oc: object -> course
  gemm_xs<<<(NOn + 31) / 32, 256, 0, stream>>>(h_object, W_oc, inv_out_oc, xs, NOn);
  scatter_add<<<(EOCn * 16 + 255) / 256, 256, 0, stream>>>(xs, src_oc, dst_oc, inv_in_oc, g_c, EOCn);
  // relation oe: object -> enrollment
  gemm_xs<<<(NOn + 31) / 32, 256, 0, stream>>>(h_object, W_oe, inv_out_oe, xs, NOn);
  scatter_add<<<(EOEn * 16 + 255) / 256, 256, 0, stream>>>(xs, src_oe, dst_oe, inv_in_oe, g_e, EOEn);

  // fuse + GRU (reads sp from gate region, overwrites it with gates)
  fuse_update<<<(NCn + 31) / 32, 256, 0, stream>>>(g_c, h1_course, h2_course, b_oc, nullptr,
                                                   gate_W, gate_b, W_ih, W_hh, b_ih, b_hh,
                                                   out_c, g_c, NCn);
  fuse_update<<<(NOn + 31) / 32, 256, 0, stream>>>(g_o, h1_object, h2_object, b_co, b_eo,
                                                   gate_W, gate_b, W_ih, W_hh, b_ih, b_hh,
                                                   out_o, g_o, NOn);
  fuse_update<<<(NEn + 31) / 32, 256, 0, stream>>>(g_e, h1_enroll, h2_enroll, b_oe, nullptr,
                                                   gate_W, gate_b, W_ih, W_hh, b_ih, b_hh,
                                                   out_e, g_e, NEn);
}

// Round 2
// 3621.334 us; speedup vs baseline: 1.4685x; 1.4685x over previous
//
#include <hip/hip_runtime.h>
#include <hip/hip_bf16.h>

#define NCn 2000
#define NOn 100000
#define NEn 200000
#define Dn  128
#define ECOn 100000
#define EOCn 100000
#define EEOn 200000
#define EOEn 200000

typedef __bf16 bf16x8 __attribute__((ext_vector_type(8)));
typedef float f32x4 __attribute__((ext_vector_type(4)));
typedef unsigned short u16x8 __attribute__((ext_vector_type(8)));

__device__ inline unsigned short f2bf(float f) {
  return __builtin_bit_cast(unsigned short, (__bf16)f);
}
__device__ inline float bf2f(unsigned short u) {
  unsigned int x = ((unsigned int)u) << 16;
  return __builtin_bit_cast(float, x);
}
__device__ inline u16x8 cvt8(float4 a, float4 b) {
  u16x8 o;
  o[0] = f2bf(a.x); o[1] = f2bf(a.y); o[2] = f2bf(a.z); o[3] = f2bf(a.w);
  o[4] = f2bf(b.x); o[5] = f2bf(b.y); o[6] = f2bf(b.z); o[7] = f2bf(b.w);
  return o;
}
__device__ inline f32x4 mfma16(bf16x8 a, bf16x8 b, f32x4 c) {
  return __builtin_amdgcn_mfma_f32_16x16x32_bf16(a, b, c, 0, 0, 0);
}
__device__ inline bf16x8 g16(const unsigned short* p) {
  return __builtin_bit_cast(bf16x8, *(const u16x8*)p);
}
__device__ inline float sigm(float x) { return 1.f / (1.f + __expf(-x)); }

// XOR swizzle in ushort-index space: XOR bits 3..5 with row&7 (byte bits 4..6)
#define CATI(r, c) ((r) * 384 + ((c) ^ (((r) & 7) << 3)))
#define FUSI(r, c) ((r) * 128 + ((c) ^ (((r) & 7) << 3)))
#define XLI(r, c)  ((r) * 128 + ((c) ^ (((r) & 7) << 3)))

// ---------------- degree counting ----------------
__global__ __launch_bounds__(256) void deg_count(const int* __restrict__ src,
                                                 const int* __restrict__ dst,
                                                 int n, float* __restrict__ dout,
                                                 float* __restrict__ din) {
  int i = blockIdx.x * 256 + threadIdx.x;
  if (i < n) {
    atomicAdd(&dout[src[i]], 1.0f);
    atomicAdd(&din[dst[i]], 1.0f);
  }
}

__global__ __launch_bounds__(256) void deg_fin(float* __restrict__ d, int n) {
  int i = blockIdx.x * 256 + threadIdx.x;
  if (i < n) d[i] = rsqrtf(fmaxf(d[i], 1.0f));
}

// ---------------- weight pre-convert to bf16 (+ combined biases) ----------------
// wb layout (ushorts): [0) Wt_co [16384) Wt_oc [32768) Wt_eo [49152) Wt_oe
//   (transposed: Wt[j*128+k] = W[k*128+j])
// [65536) GWb 128x384   [114688) WIHb 384x128   [163840) WHHb 384x128  -> 212992
// bsum (floats): [0..128) course=b_oc, [128..256) object=b_co+b_eo, [256..384) enroll=b_oe
__global__ __launch_bounds__(256) void conv_weights(
    const float* __restrict__ Wco, const float* __restrict__ Woc,
    const float* __restrict__ Weo, const float* __restrict__ Woe,
    const float* __restrict__ GW, const float* __restrict__ WIH,
    const float* __restrict__ WHH,
    const float* __restrict__ b_co, const float* __restrict__ b_oc,
    const float* __restrict__ b_eo, const float* __restrict__ b_oe,
    unsigned short* __restrict__ wb, float* __restrict__ bsum) {
  int i = blockIdx.x * 256 + threadIdx.x;
  if (i < 65536) {
    int rel = i >> 14, idx = i & 16383;
    int j = idx >> 7, k = idx & 127;
    const float* W = (rel == 0) ? Wco : (rel == 1) ? Woc : (rel == 2) ? Weo : Woe;
    wb[i] = f2bf(W[k * 128 + j]);
  } else if (i < 65536 + 3 * 49152) {
    int i2 = i - 65536;
    const float* S = (i2 < 49152) ? GW : (i2 < 98304) ? WIH : WHH;
    wb[i] = f2bf(S[i2 % 49152]);
  } else if (i < 212992 + 384) {
    int c = i - 212992;
    float v;
    if (c < 128) v = b_oc[c];
    else if (c < 256) v = b_co[c - 128] + b_eo[c - 128];
    else v = b_oe[c - 256];
    bsum[c] = v;
  }
}

// ---------------- xs = (X * inv_out[:,None]) @ W   (MFMA bf16) ----------------
// 64 rows/block, 4 waves; wave w owns rows [16w,16w+16). N=128 (8 tiles), K=128.
__global__ __launch_bounds__(256) void gemm_xs_mfma(
    const float* __restrict__ X, const unsigned short* __restrict__ Wt,
    const float* __restrict__ inv_out, float* __restrict__ XS, int n) {
  __shared__ __align__(16) unsigned short xl[64 * 128];
  int tid = threadIdx.x;
  int lane = tid & 63, w = tid >> 6;
  int base = blockIdx.x * 64;
  for (int i = tid * 8; i < 64 * 128; i += 2048) {
    int row = i >> 7, c = i & 127;
    int r = base + row;
    u16x8 o = {0, 0, 0, 0, 0, 0, 0, 0};
    if (r < n) {
      float s = inv_out[r];
      float4 a0 = *(const float4*)&X[(size_t)r * 128 + c];
      float4 a1 = *(const float4*)&X[(size_t)r * 128 + c + 4];
      a0.x *= s; a0.y *= s; a0.z *= s; a0.w *= s;
      a1.x *= s; a1.y *= s; a1.z *= s; a1.w *= s;
      o = cvt8(a0, a1);
    }
    *(u16x8*)&xl[XLI(row, c)] = o;
  }
  __syncthreads();
  int ml = lane & 15, kg = lane >> 4;
  int arow = 16 * w + ml;
  f32x4 acc[8] = {};
  for (int ks = 0; ks < 4; ++ks) {
    int k0 = ks * 32 + kg * 8;
    bf16x8 a = __builtin_bit_cast(bf16x8, *(u16x8*)&xl[XLI(arow, k0)]);
#pragma unroll
    for (int tn = 0; tn < 8; ++tn) {
      bf16x8 b = g16(&Wt[(16 * tn + ml) * 128 + k0]);
      acc[tn] = mfma16(a, b, acc[tn]);
    }
  }
#pragma unroll
  for (int tn = 0; tn < 8; ++tn) {
    int col = 16 * tn + ml;
#pragma unroll
    for (int e = 0; e < 4; ++e) {
      int node = base + 16 * w + kg * 4 + e;
      if (node < n) XS[(size_t)node * 128 + col] = acc[tn][e];
    }
  }
}

// ---------------- scatter: SP[dst] += XS[src] * inv_in[dst] ----------------
__global__ __launch_bounds__(256) void scatter_add(const float* __restrict__ XS,
                                                   const int* __restrict__ src,
                                                   const int* __restrict__ dst,
                                                   const float* __restrict__ inv_in,
                                                   float* __restrict__ SP, int n) {
  int t = blockIdx.x * 256 + threadIdx.x;
  int e = t >> 4;
  if (e >= n) return;
  int sg = t & 15;
  int s = src[e], d = dst[e];
  float w = inv_in[d];
  const float* xr = &XS[(size_t)s * 128 + sg * 8];
  float* op = &SP[(size_t)d * 128 + sg * 8];
  float4 v0 = *(const float4*)xr;
  float4 v1 = *(const float4*)(xr + 4);
  atomicAdd(op + 0, v0.x * w);
  atomicAdd(op + 1, v0.y * w);
  atomicAdd(op + 2, v0.z * w);
  atomicAdd(op + 3, v0.w * w);
  atomicAdd(op + 4, v1.x * w);
  atomicAdd(op + 5, v1.y * w);
  atomicAdd(op + 6, v1.z * w);
  atomicAdd(op + 7, v1.w * w);
}

// ---------------- fuse + GRU (MFMA bf16) ----------------
// 64 nodes/block, 4 waves; wave w owns node rows [16w,16w+16).
// cat (LDS bf16, swizzled): [0:128)=sp+bias, [128:256)=h1, [256:384)=h2
__global__ __launch_bounds__(256) void fuse_mfma(
    const float* __restrict__ SP, const float* __restrict__ H1,
    const float* __restrict__ H2, const float* __restrict__ BIAS,
    const unsigned short* __restrict__ GWb, const float* __restrict__ gb,
    const unsigned short* __restrict__ WIHb, const unsigned short* __restrict__ WHHb,
    const float* __restrict__ bih, const float* __restrict__ bhh,
    float* __restrict__ OUT, float* __restrict__ GOUT, int n) {
  __shared__ __align__(16) unsigned short catl[64 * 384];
  __shared__ __align__(16) unsigned short fusl[64 * 128];
  int tid = threadIdx.x;
  int lane = tid & 63, w = tid >> 6;
  int base = blockIdx.x * 64;

  // ---- stage cat = [sp+bias | h1 | h2] as bf16 ----
  for (int i = tid * 8; i < 64 * 384; i += 2048) {
    int row = i / 384;
    int c = i - row * 384;
    int r = base + row;
    u16x8 o = {0, 0, 0, 0, 0, 0, 0, 0};
    if (r < n) {
      if (c < 128) {
        float4 a0 = *(const float4*)&SP[(size_t)r * 128 + c];
        float4 a1 = *(const float4*)&SP[(size_t)r * 128 + c + 4];
        float4 b0 = *(const float4*)&BIAS[c];
        float4 b1 = *(const float4*)&BIAS[c + 4];
        a0.x += b0.x; a0.y += b0.y; a0.z += b0.z; a0.w += b0.w;
        a1.x += b1.x; a1.y += b1.y; a1.z += b1.z; a1.w += b1.w;
        o = cvt8(a0, a1);
      } else {
        const float* src = (c < 256) ? &H1[(size_t)r * 128 + (c - 128)]
                                     : &H2[(size_t)r * 128 + (c - 256)];
        float4 a0 = *(const float4*)src;
        float4 a1 = *(const float4*)(src + 4);
        o = cvt8(a0, a1);
      }
    }
    *(u16x8*)&catl[CATI(row, c)] = o;
  }
  __syncthreads();

  int ml = lane & 15, kg = lane >> 4;
  int arow = 16 * w + ml;  // LDS row for A-fragments

  // ---- gate = sigmoid(cat @ gate_W.T + gb); K=384 ----
  f32x4 accg[8] = {};
  for (int ks = 0; ks < 12; ++ks) {
    int k0 = ks * 32 + kg * 8;
    bf16x8 a = __builtin_bit_cast(bf16x8, *(u16x8*)&catl[CATI(arow, k0)]);
#pragma unroll
    for (int tn = 0; tn < 8; ++tn) {
      bf16x8 b = g16(&GWb[(16 * tn + ml) * 384 + k0]);
      accg[tn] = mfma16(a, b, accg[tn]);
    }
  }
  // epilogue: gate, fused; write GOUT + fusl
#pragma unroll
  for (int tn = 0; tn < 8; ++tn) {
    int col = 16 * tn + ml;
    float gbv = gb[col];
#pragma unroll
    for (int e = 0; e < 4; ++e) {
      int row16 = kg * 4 + e;
      int lrow = 16 * w + row16;
      float g = sigm(accg[tn][e] + gbv);
      float h1v = bf2f(catl[CATI(lrow, 128 + col)]);
      float h2v = bf2f(catl[CATI(lrow, 256 + col)]);
      float fu = fmaf(g, h1v - h2v, h2v);
      fusl[FUSI(lrow, col)] = f2bf(fu);
      int node = base + lrow;
      if (node < n) GOUT[(size_t)node * 128 + col] = g;
    }
  }
  __syncthreads();

  // ---- GRU: gi = sp @ W_ih.T, gh = fused @ W_hh.T, chunks r,z,n ----
  f32x4 rr[8], zz[8];
#pragma unroll
  for (int c = 0; c < 2; ++c) {
    f32x4 ai[8] = {}, ah[8] = {};
    for (int ks = 0; ks < 4; ++ks) {
      int k0 = ks * 32 + kg * 8;
      bf16x8 asp = __builtin_bit_cast(bf16x8, *(u16x8*)&catl[CATI(arow, k0)]);
      bf16x8 afu = __builtin_bit_cast(bf16x8, *(u16x8*)&fusl[FUSI(arow, k0)]);
#pragma unroll
      for (int tn = 0; tn < 8; ++tn) {
        int rrow = c * 128 + 16 * tn + ml;
        bf16x8 bi = g16(&WIHb[rrow * 128 + k0]);
        bf16x8 bh = g16(&WHHb[rrow * 128 + k0]);
        ai[tn] = mfma16(asp, bi, ai[tn]);
        ah[tn] = mfma16(afu, bh, ah[tn]);
      }
    }
#pragma unroll
    for (int tn = 0; tn < 8; ++tn) {
      int col = c * 128 + 16 * tn + ml;
      float bi = bih[col], bh = bhh[col];
#pragma unroll
      for (int e = 0; e < 4; ++e) {
        float s = sigm(ai[tn][e] + bi + ah[tn][e] + bh);
        if (c == 0) rr[tn][e] = s; else zz[tn][e] = s;
      }
    }
  }
  {  // n-chunk + output
    f32x4 ai[8] = {}, ah[8] = {};
    for (int ks = 0; ks < 4; ++ks) {
      int k0 = ks * 32 + kg * 8;
      bf16x8 asp = __builtin_bit_cast(bf16x8, *(u16x8*)&catl[CATI(arow, k0)]);
      bf16x8 afu = __builtin_bit_cast(bf16x8, *(u16x8*)&fusl[FUSI(arow, k0)]);
#pragma unroll
      for (int tn = 0; tn < 8; ++tn) {
        int rrow = 256 + 16 * tn + ml;
        bf16x8 bi = g16(&WIHb[rrow * 128 + k0]);
        bf16x8 bh = g16(&WHHb[rrow * 128 + k0]);
        ai[tn] = mfma16(asp, bi, ai[tn]);
        ah[tn] = mfma16(afu, bh, ah[tn]);
      }
    }
#pragma unroll
    for (int tn = 0; tn < 8; ++tn) {
      int col2 = 256 + 16 * tn + ml;
      float bi = bih[col2], bh = bhh[col2];
      int ocol = 16 * tn + ml;
#pragma unroll
      for (int e = 0; e < 4; ++e) {
        int row16 = kg * 4 + e;
        int lrow = 16 * w + row16;
        float x = (ai[tn][e] + bi) + rr[tn][e] * (ah[tn][e] + bh);
        x = fminf(fmaxf(x, -15.f), 15.f);
        float ex = __expf(2.f * x);
        float nv = (ex - 1.f) / (ex + 1.f);
        float fu = bf2f(fusl[FUSI(lrow, ocol)]);
        float ht = fmaf(zz[tn][e], fu - nv, nv);
        ht = fmaxf(ht, 0.f);
        int node = base + lrow;
        if (node < n) OUT[(size_t)node * 128 + ocol] = ht;
      }
    }
  }
}

extern "C" void kernel_launch(void* const* d_in, const int* in_sizes, int n_in,
                              void* d_out, int out_size, void* d_ws, size_t ws_size,
                              hipStream_t stream) {
  const float* h_course = (const float*)d_in[0];
  const float* h_object = (const float*)d_in[1];
  const float* h_enroll = (const float*)d_in[2];
  const float* h1_course = (const float*)d_in[3];
  const float* h1_object = (const float*)d_in[4];
  const float* h1_enroll = (const float*)d_in[5];
  const float* h2_course = (const float*)d_in[6];
  const float* h2_object = (const float*)d_in[7];
  const float* h2_enroll = (const float*)d_in[8];
  const int* src_co = (const int*)d_in[9];
  const int* dst_co = (const int*)d_in[10];
  const int* src_oc = (const int*)d_in[11];
  const int* dst_oc = (const int*)d_in[12];
  const int* src_eo = (const int*)d_in[13];
  const int* dst_eo = (const int*)d_in[14];
  const int* src_oe = (const int*)d_in[15];
  const int* dst_oe = (const int*)d_in[16];
  const float* W_co = (const float*)d_in[17];
  const float* b_co = (const float*)d_in[18];
  const float* W_oc = (const float*)d_in[19];
  const float* b_oc = (const float*)d_in[20];
  const float* W_eo = (const float*)d_in[21];
  const float* b_eo = (const float*)d_in[22];
  const float* W_oe = (const float*)d_in[23];
  const float* b_oe = (const float*)d_in[24];
  const float* gate_W = (const float*)d_in[25];
  const float* gate_b = (const float*)d_in[26];
  const float* W_ih = (const float*)d_in[27];
  const float* W_hh = (const float*)d_in[28];
  const float* b_ih = (const float*)d_in[29];
  const float* b_hh = (const float*)d_in[30];

  float* out = (float*)d_out;
  float* out_c = out;
  float* out_o = out + (size_t)NCn * Dn;
  float* out_e = out + (size_t)(NCn + NOn) * Dn;
  float* g_c = out + (size_t)(NCn + NOn + NEn) * Dn;  // gate region doubles as sp accum
  float* g_o = g_c + (size_t)NCn * Dn;
  float* g_e = g_o + (size_t)NOn * Dn;

  // scratch carved from out region (dead until fuse writes land)
  float* xs = out;                      // up to NE*D floats
  float* deg = out + (size_t)NEn * Dn;  // 804000 floats
  float* inv_out_co = deg;
  float* inv_in_co = deg + 2000;
  float* inv_out_oc = deg + 102000;
  float* inv_in_oc = deg + 202000;
  float* inv_out_eo = deg + 204000;
  float* inv_in_eo = deg + 404000;
  float* inv_out_oe = deg + 504000;
  float* inv_in_oe = deg + 604000;

  // bf16 weights + combined biases in d_ws (~428 KB)
  unsigned short* wb = (unsigned short*)d_ws;
  float* bsum = (float*)((char*)d_ws + 212992 * sizeof(unsigned short));
  const unsigned short* Wt_co = wb;
  const unsigned short* Wt_oc = wb + 16384;
  const unsigned short* Wt_eo = wb + 32768;
  const unsigned short* Wt_oe = wb + 49152;
  const unsigned short* GWb = wb + 65536;
  const unsigned short* WIHb = wb + 114688;
  const unsigned short* WHHb = wb + 163840;

  hipMemsetAsync(deg, 0, 804000 * sizeof(float), stream);
  hipMemsetAsync(g_c, 0, (size_t)(NCn + NOn + NEn) * Dn * sizeof(float), stream);

  conv_weights<<<834, 256, 0, stream>>>(W_co, W_oc, W_eo, W_oe, gate_W, W_ih, W_hh,
                                        b_co, b_oc, b_eo, b_oe, wb, bsum);

  deg_count<<<(ECOn + 255) / 256, 256, 0, stream>>>(src_co, dst_co, ECOn, inv_out_co, inv_in_co);
  deg_count<<<(EOCn + 255) / 256, 256, 0, stream>>>(src_oc, dst_oc, EOCn, inv_out_oc, inv_in_oc);
  deg_count<<<(EEOn + 255) / 256, 256, 0, stream>>>(src_eo, dst_eo, EEOn, inv_out_eo, inv_in_eo);
  deg_count<<<(EOEn + 255) / 256, 256, 0, stream>>>(src_oe, dst_oe, EOEn, inv_out_oe, inv_in_oe);
  deg_fin<<<(804000 + 255) / 256, 256, 0, stream>>>(deg, 804000);

  // relation co: course -> object
  gemm_xs_mfma<<<(NCn + 63) / 64, 256, 0, stream>>>(h_course, Wt_co, inv_out_co, xs, NCn);
  scatter_add<<<(ECOn * 16 + 255) / 256, 256, 0, stream>>>(xs, src_co, dst_co, inv_in_co, g_o, ECOn);
  // relation eo: enrollment -> object
  gemm_xs_mfma<<<(NEn + 63) / 64, 256, 0, stream>>>(h_enroll, Wt_eo, inv_out_eo, xs, NEn);
  scatter_add<<<(EEOn * 16 + 255) / 256, 256, 0, stream>>>(xs, src_eo, dst_eo, inv_in_eo, g_o, EEOn);
  // relation oc: object -> course
  gemm_xs_mfma<<<(NOn + 63) / 64, 256, 0, stream>>>(h_object, Wt_oc, inv_out_oc, xs, NOn);
  scatter_add<<<(EOCn * 16 + 255) / 256, 256, 0, stream>>>(xs, src_oc, dst_oc, inv_in_oc, g_c, EOCn);
  // relation oe: object -> enrollment
  gemm_xs_mfma<<<(NOn + 63) / 64, 256, 0, stream>>>(h_object, Wt_oe, inv_out_oe, xs, NOn);
  scatter_add<<<(EOEn * 16 + 255) / 256, 256, 0, stream>>>(xs, src_oe, dst_oe, inv_in_oe, g_e, EOEn);

  // fuse + GRU
  fuse_mfma<<<(NCn + 63) / 64, 256, 0, stream>>>(g_c, h1_course, h2_course, bsum,
                                                 GWb, gate_b, WIHb, WHHb, b_ih, b_hh,
                                                 out_c, g_c, NCn);
  fuse_mfma<<<(NOn + 63) / 64, 256, 0, stream>>>(g_o, h1_object, h2_object, bsum + 128,
                                                 GWb, gate_b, WIHb, WHHb, b_ih, b_hh,
                                                 out_o, g_o, NOn);
  fuse_mfma<<<(NEn + 63) / 64, 256, 0, stream>>>(g_e, h1_enroll, h2_enroll, bsum + 256,
                                                 GWb, gate_b, WIHb, WHHb, b_ih, b_hh,
                                                 out_e, g_e, NEn);
}

// Round 4
// 808.470 us; speedup vs baseline: 6.5779x; 4.4792x over previous
//
#include <hip/hip_runtime.h>
#include <hip/hip_bf16.h>
#include <stdint.h>

#define NCn 2000
#define NOn 100000
#define NEn 200000
#define ECOn 100000
#define EOCn 100000
#define EEOn 200000
#define EOEn 200000
#define NDST 402000   // dst segs: co@0(NO) oc@100000(NC) eo@102000(NO) oe@202000(NE)
#define NSRC 402000   // src segs: co@0(NC) oc@2000(NO) eo@102000(NE) oe@302000(NO)
#define NB1 1571      // ceil(402000/256)

typedef __bf16 bf16x8 __attribute__((ext_vector_type(8)));
typedef float f32x4 __attribute__((ext_vector_type(4)));
typedef unsigned short u16x8 __attribute__((ext_vector_type(8)));

__device__ inline unsigned short f2bf(float f) {
  return __builtin_bit_cast(unsigned short, (__bf16)f);
}
__device__ inline float bf2f(unsigned short u) {
  unsigned int x = ((unsigned int)u) << 16;
  return __builtin_bit_cast(float, x);
}
__device__ inline u16x8 cvt8(float4 a, float4 b) {
  u16x8 o;
  o[0] = f2bf(a.x); o[1] = f2bf(a.y); o[2] = f2bf(a.z); o[3] = f2bf(a.w);
  o[4] = f2bf(b.x); o[5] = f2bf(b.y); o[6] = f2bf(b.z); o[7] = f2bf(b.w);
  return o;
}
__device__ inline f32x4 mfma16(bf16x8 a, bf16x8 b, f32x4 c) {
  return __builtin_amdgcn_mfma_f32_16x16x32_bf16(a, b, c, 0, 0, 0);
}
__device__ inline bf16x8 g16(const unsigned short* p) {
  return __builtin_bit_cast(bf16x8, *(const u16x8*)p);
}
__device__ inline float sigm(float x) { return 1.f / (1.f + __expf(-x)); }

// XOR swizzle (ushort-index space): XOR col bits 3..5 with row&7 -> byte bits 4..6
#define XLI(r, c) ((r) * 128 + ((c) ^ (((r) & 7) << 3)))

// ---------------- CSR build ----------------
__global__ __launch_bounds__(256) void count2(const int* __restrict__ src,
                                              const int* __restrict__ dst, int n,
                                              int* __restrict__ cs, int* __restrict__ cd) {
  int i = blockIdx.x * 256 + threadIdx.x;
  if (i < n) {
    atomicAdd(&cs[src[i]], 1);
    atomicAdd(&cd[dst[i]], 1);
  }
}

__global__ __launch_bounds__(256) void scan1(const int* __restrict__ in, int* __restrict__ ex,
                                             int* __restrict__ bsum, int n) {
  __shared__ int s[256];
  int t = threadIdx.x, i = blockIdx.x * 256 + t;
  int v = (i < n) ? in[i] : 0;
  s[t] = v;
  for (int d = 1; d < 256; d <<= 1) {
    __syncthreads();
    int x = (t >= d) ? s[t - d] : 0;
    __syncthreads();
    s[t] += x;
  }
  __syncthreads();
  if (i < n) ex[i] = s[t] - v;
  if (t == 255) bsum[blockIdx.x] = s[255];
}

__global__ __launch_bounds__(256) void scan2(const int* __restrict__ bs, int* __restrict__ be, int nb) {
  __shared__ int s[256];
  __shared__ int carry;
  int t = threadIdx.x;
  if (t == 0) carry = 0;
  for (int t0 = 0; t0 < nb; t0 += 256) {
    int i = t0 + t;
    int v = (i < nb) ? bs[i] : 0;
    s[t] = v;
    for (int d = 1; d < 256; d <<= 1) {
      __syncthreads();
      int x = (t >= d) ? s[t - d] : 0;
      __syncthreads();
      s[t] += x;
    }
    __syncthreads();
    int c0 = carry;
    if (i < nb) be[i] = s[t] - v + c0;
    __syncthreads();
    if (t == 0) carry = c0 + s[255];
    __syncthreads();
  }
}

__global__ __launch_bounds__(256) void scan3(int* __restrict__ off, const int* __restrict__ be, int n) {
  int i = blockIdx.x * 256 + threadIdx.x;
  if (i < n) off[i] += be[blockIdx.x];
}

__global__ __launch_bounds__(256) void fillk(const int* __restrict__ src, const int* __restrict__ dst,
                                             int n, int* __restrict__ offseg, int* __restrict__ srcs) {
  int i = blockIdx.x * 256 + threadIdx.x;
  if (i < n) {
    int pos = atomicAdd(&offseg[dst[i]], 1);
    srcs[pos] = src[i];
  }
}

// ---------------- fused-weight precompute ----------------
// P[rel][k][j] (j<128: W_rel @ Wg1.T; j in [128,512): W_rel @ W_ih[j-128].T)
__global__ __launch_bounds__(256) void wgemmP(const float* __restrict__ Wco, const float* __restrict__ Woc,
                                              const float* __restrict__ Weo, const float* __restrict__ Woe,
                                              const float* __restrict__ GW, const float* __restrict__ WIH,
                                              float* __restrict__ P) {
  int idx = blockIdx.x * 256 + threadIdx.x;  // 4*128*512
  int rel = idx >> 16, r2 = idx & 65535, k = r2 >> 9, j = r2 & 511;
  const float* W = (rel == 0) ? Wco : (rel == 1) ? Woc : (rel == 2) ? Weo : Woe;
  const float* wr = &W[k * 128];
  const float* q = (j < 128) ? &GW[j * 384] : &WIH[(j - 128) * 128];
  float s = 0.f;
  for (int m = 0; m < 128; m += 4) {
    float4 a = *(const float4*)&wr[m];
    float4 b = *(const float4*)&q[m];
    s = fmaf(a.x, b.x, fmaf(a.y, b.y, fmaf(a.z, b.z, fmaf(a.w, b.w, s))));
  }
  P[idx] = s;
}

// colbias[type][512]: gate: gate_b + b@Wg1.T; r/z: b_ih+b_hh+b@Wih_c.T; n: b_ih+b@Wih_n.T
__global__ __launch_bounds__(256) void cbias(const float* __restrict__ GW, const float* __restrict__ WIH,
                                             const float* __restrict__ gate_b, const float* __restrict__ b_ih,
                                             const float* __restrict__ b_hh, const float* __restrict__ b_co,
                                             const float* __restrict__ b_oc, const float* __restrict__ b_eo,
                                             const float* __restrict__ b_oe, float* __restrict__ cb) {
  int idx = blockIdx.x * 256 + threadIdx.x;
  if (idx >= 1536) return;
  int type = idx / 512, j = idx & 511;
  float s = 0.f;
  for (int m = 0; m < 128; ++m) {
    float bm = (type == 0) ? b_oc[m] : (type == 1) ? (b_co[m] + b_eo[m]) : b_oe[m];
    float qm = (j < 128) ? GW[j * 384 + m] : WIH[(j - 128) * 128 + m];
    s = fmaf(bm, qm, s);
  }
  if (j < 128) s += gate_b[j];
  else {
    s += b_ih[j - 128];
    if (j < 384) s += b_hh[j - 128];  // b_hh folded for r,z only (n keeps it separate)
  }
  cb[idx] = s;
}

// ---------------- weight stream pack (fragment-ordered chunks) ----------------
// chunk = 16KB = [s:2][tn:8][lane:64][e:8] bf16, K=64 per chunk.
// type chunk bases: course 0..17, object 18..43, enroll 44..61.
__global__ __launch_bounds__(256) void packk(const float* __restrict__ P, const float* __restrict__ GW,
                                             const float* __restrict__ WHH, unsigned short* __restrict__ strm) {
  int g = blockIdx.x * 256 + threadIdx.x;  // 63488 groups of 8
  int chunk = g >> 10, within = g & 1023;
  int s = within >> 9, rem = within & 511, tn = rem >> 6, ln = rem & 63;
  int ml = ln & 15, kg = ln >> 4, col = tn * 16 + ml;
  int type, lc;
  if (chunk < 18) { type = 0; lc = chunk; }
  else if (chunk < 44) { type = 1; lc = chunk - 18; }
  else { type = 2; lc = chunk - 44; }
  int nrel = (type == 1) ? 2 : 1;
  int rel0 = (type == 0) ? 1 : (type == 1) ? 0 : 3;
  int rel1 = 2;  // object's second relation (eo)
  int gateN = 2 * nrel + 4;
  int mode, rel = 0, cc = 0, kb = 0;
  if (lc < 2 * nrel) { mode = 0; rel = (lc >> 1) ? rel1 : rel0; kb = (lc & 1) * 64; }
  else if (lc < 2 * nrel + 2) { mode = 1; kb = ((lc - 2 * nrel) & 1) * 64; }
  else if (lc < gateN) { mode = 2; kb = ((lc - 2 * nrel - 2) & 1) * 64; }
  else {
    int l2 = lc - gateN, per = 2 * nrel + 2;
    cc = l2 / per;
    int l3 = l2 % per;
    if (l3 < 2 * nrel) { mode = 3; rel = (l3 >> 1) ? rel1 : rel0; kb = (l3 & 1) * 64; }
    else { mode = 4; kb = ((l3 - 2 * nrel) & 1) * 64; }
  }
  u16x8 o;
#pragma unroll
  for (int e = 0; e < 8; ++e) {
    int k = kb + s * 32 + kg * 8 + e;
    float v;
    if (mode == 0) v = P[((rel * 128) + k) * 512 + col];
    else if (mode == 1) v = GW[col * 384 + 128 + k];
    else if (mode == 2) v = GW[col * 384 + 256 + k];
    else if (mode == 3) v = P[((rel * 128) + k) * 512 + 128 + cc * 128 + col];
    else v = WHH[(cc * 128 + col) * 128 + k];
    o[e] = f2bf(v);
  }
  *(u16x8*)&strm[(size_t)g * 8] = o;
}

// ---------------- gather aggregation into A-fragments ----------------
__device__ inline void gather_rel(const float* __restrict__ H, const int* __restrict__ cd,
                                  const int* __restrict__ offend, const int* __restrict__ cs,
                                  const int* __restrict__ srcs, int grow, int n, int kg,
                                  bf16x8 out[4]) {
  float ac[4][8];
#pragma unroll
  for (int a = 0; a < 4; ++a)
#pragma unroll
    for (int b = 0; b < 8; ++b) ac[a][b] = 0.f;
  if (grow < n) {
    int c = cd[grow];
    int end = offend[grow];
    for (int e = end - c; e < end; ++e) {
      int s = srcs[e];
      float sc = rsqrtf(fmaxf((float)cs[s], 1.f));
      const float4* hp = (const float4*)&H[(size_t)s * 128 + kg * 8];
#pragma unroll
      for (int ks = 0; ks < 4; ++ks) {
        float4 v0 = hp[ks * 8], v1 = hp[ks * 8 + 1];
        ac[ks][0] = fmaf(v0.x, sc, ac[ks][0]);
        ac[ks][1] = fmaf(v0.y, sc, ac[ks][1]);
        ac[ks][2] = fmaf(v0.z, sc, ac[ks][2]);
        ac[ks][3] = fmaf(v0.w, sc, ac[ks][3]);
        ac[ks][4] = fmaf(v1.x, sc, ac[ks][4]);
        ac[ks][5] = fmaf(v1.y, sc, ac[ks][5]);
        ac[ks][6] = fmaf(v1.z, sc, ac[ks][6]);
        ac[ks][7] = fmaf(v1.w, sc, ac[ks][7]);
      }
    }
    float iv = rsqrtf(fmaxf((float)c, 1.f));
#pragma unroll
    for (int ks = 0; ks < 4; ++ks)
#pragma unroll
      for (int b = 0; b < 8; ++b) ac[ks][b] *= iv;
  }
#pragma unroll
  for (int ks = 0; ks < 4; ++ks)
    out[ks] = __builtin_bit_cast(
        bf16x8, cvt8(make_float4(ac[ks][0], ac[ks][1], ac[ks][2], ac[ks][3]),
                     make_float4(ac[ks][4], ac[ks][5], ac[ks][6], ac[ks][7])));
}

// A-fragment from LDS: lane (ml,kg) needs cols kbase + kg*8 .. +7 of its row.
// (Round-3 bug: kg*8 was missing -> every LDS-sourced fragment was wrong.)
__device__ inline bf16x8 ldsA(const unsigned short* L, int arow, int kbase, int kg) {
  return __builtin_bit_cast(bf16x8, *(const u16x8*)&L[XLI(arow, kbase + kg * 8)]);
}

// ---------------- fused GNN layer kernel ----------------
// 128 nodes/block, 8 waves x 16 rows. Double-buffered fragment-ordered weight
// stream through LDS (one __syncthreads per 16KB chunk, reg-staged prefetch).
#define PHASE(P, A0, A1, ACC)                                                  \
  do {                                                                         \
    __syncthreads();                                                           \
    {                                                                          \
      int nb_ = (((P) + 1) & 1) * 8192;                                        \
      *(u16x8*)&wl[nb_ + tid * 8] = rA0;                                       \
      *(u16x8*)&wl[nb_ + 4096 + tid * 8] = rA1;                                \
      if ((P) + 2 < NCH) {                                                     \
        const unsigned short* sp_ = stream + (size_t)((P) + 2) * 8192;         \
        rA0 = *(const u16x8*)&sp_[tid * 8];                                    \
        rA1 = *(const u16x8*)&sp_[4096 + tid * 8];                             \
      }                                                                        \
    }                                                                          \
    {                                                                          \
      int cb_ = ((P) & 1) * 8192;                                              \
      _Pragma("unroll") for (int s_ = 0; s_ < 2; ++s_) {                       \
        bf16x8 a_ = (s_ ? (A1) : (A0));                                        \
        const unsigned short* wb_ = &wl[cb_ + s_ * 4096 + lane * 8];           \
        _Pragma("unroll") for (int tn_ = 0; tn_ < 8; ++tn_) {                  \
          bf16x8 b_ = g16(wb_ + tn_ * 512);                                    \
          ACC[tn_] = mfma16(a_, b_, ACC[tn_]);                                 \
        }                                                                      \
      }                                                                        \
    }                                                                          \
  } while (0)

template <int NREL>
__global__ __launch_bounds__(512, 2) void fuse_kernel(
    const float* __restrict__ H1, const float* __restrict__ H2,
    const float* __restrict__ Hs0, const int* __restrict__ cd0,
    const int* __restrict__ off0, const int* __restrict__ cs0,
    const float* __restrict__ Hs1, const int* __restrict__ cd1,
    const int* __restrict__ off1, const int* __restrict__ cs1,
    const int* __restrict__ srcs, const unsigned short* __restrict__ stream,
    const float* __restrict__ cb, const float* __restrict__ bhh,
    float* __restrict__ OUT, float* __restrict__ GOUT, int n) {
  constexpr int NCH = (NREL == 1) ? 18 : 26;
  __shared__ __align__(16) unsigned short A1l[16384];  // h1, later fused
  __shared__ __align__(16) unsigned short A2l[16384];  // h2
  __shared__ __align__(16) unsigned short wl[16384];   // 2 x 16KB weight chunks
  int tid = threadIdx.x, lane = tid & 63, w = tid >> 6;
  int ml = lane & 15, kg = lane >> 4;
  int base = blockIdx.x * 128;
  int arow = 16 * w + ml;

  // prefetch weight chunks 0 and 1
  u16x8 rA0 = *(const u16x8*)&stream[tid * 8];
  u16x8 rA1 = *(const u16x8*)&stream[4096 + tid * 8];
  u16x8 rB0 = *(const u16x8*)&stream[8192 + tid * 8];
  u16x8 rB1 = *(const u16x8*)&stream[12288 + tid * 8];

  // stage h1/h2 tiles (bf16, swizzled)
  for (int i = tid * 8; i < 16384; i += 4096) {
    int row = i >> 7, c = i & 127;
    int r = base + row;
    u16x8 o1 = {0, 0, 0, 0, 0, 0, 0, 0}, o2 = o1;
    if (r < n) {
      const float4* p1 = (const float4*)&H1[(size_t)r * 128 + c];
      const float4* p2 = (const float4*)&H2[(size_t)r * 128 + c];
      o1 = cvt8(p1[0], p1[1]);
      o2 = cvt8(p2[0], p2[1]);
    }
    *(u16x8*)&A1l[XLI(row, c)] = o1;
    *(u16x8*)&A2l[XLI(row, c)] = o2;
  }

  // gather-aggregate neighbor features directly into MFMA A-fragments
  int grow = base + arow;
  bf16x8 agg0[4], agg1[4];
  gather_rel(Hs0, cd0, off0, cs0, srcs, grow, n, kg, agg0);
  if (NREL == 2) gather_rel(Hs1, cd1, off1, cs1, srcs, grow, n, kg, agg1);

  // commit chunk 0 to wl buf0
  *(u16x8*)&wl[tid * 8] = rA0;
  *(u16x8*)&wl[4096 + tid * 8] = rA1;
  rA0 = rB0;
  rA1 = rB1;

  // ---- gate GEMM ----
  f32x4 accg[8] = {};
  if constexpr (NREL == 1) {
    PHASE(0, agg0[0], agg0[1], accg);
    PHASE(1, agg0[2], agg0[3], accg);
    PHASE(2, ldsA(A1l, arow, 0, kg), ldsA(A1l, arow, 32, kg), accg);
    PHASE(3, ldsA(A1l, arow, 64, kg), ldsA(A1l, arow, 96, kg), accg);
    PHASE(4, ldsA(A2l, arow, 0, kg), ldsA(A2l, arow, 32, kg), accg);
    PHASE(5, ldsA(A2l, arow, 64, kg), ldsA(A2l, arow, 96, kg), accg);
  } else {
    PHASE(0, agg0[0], agg0[1], accg);
    PHASE(1, agg0[2], agg0[3], accg);
    PHASE(2, agg1[0], agg1[1], accg);
    PHASE(3, agg1[2], agg1[3], accg);
    PHASE(4, ldsA(A1l, arow, 0, kg), ldsA(A1l, arow, 32, kg), accg);
    PHASE(5, ldsA(A1l, arow, 64, kg), ldsA(A1l, arow, 96, kg), accg);
    PHASE(6, ldsA(A2l, arow, 0, kg), ldsA(A2l, arow, 32, kg), accg);
    PHASE(7, ldsA(A2l, arow, 64, kg), ldsA(A2l, arow, 96, kg), accg);
  }

  // ---- gate epilogue: g, fused (fused overwrites A1l) ----
#pragma unroll
  for (int tn = 0; tn < 8; ++tn) {
    int col = tn * 16 + ml;
    float cbv = cb[col];
#pragma unroll
    for (int e = 0; e < 4; ++e) {
      int lrow = 16 * w + kg * 4 + e;
      float gv = sigm(accg[tn][e] + cbv);
      float h1v = bf2f(A1l[XLI(lrow, col)]);
      float h2v = bf2f(A2l[XLI(lrow, col)]);
      float fu = fmaf(gv, h1v - h2v, h2v);
      A1l[XLI(lrow, col)] = f2bf(fu);
      int node = base + lrow;
      if (node < n) GOUT[(size_t)node * 128 + col] = gv;
    }
  }

  // ---- GRU chunks r, z, n ----
  constexpr int GB = (NREL == 1) ? 6 : 8;
  f32x4 rr[8], zz[8];
#pragma unroll
  for (int c = 0; c < 3; ++c) {
    f32x4 ai[8] = {}, ah[8] = {};
    if constexpr (NREL == 1) {
      PHASE(GB + c * 4 + 0, agg0[0], agg0[1], ai);
      PHASE(GB + c * 4 + 1, agg0[2], agg0[3], ai);
      PHASE(GB + c * 4 + 2, ldsA(A1l, arow, 0, kg), ldsA(A1l, arow, 32, kg), ah);
      PHASE(GB + c * 4 + 3, ldsA(A1l, arow, 64, kg), ldsA(A1l, arow, 96, kg), ah);
    } else {
      PHASE(GB + c * 6 + 0, agg0[0], agg0[1], ai);
      PHASE(GB + c * 6 + 1, agg0[2], agg0[3], ai);
      PHASE(GB + c * 6 + 2, agg1[0], agg1[1], ai);
      PHASE(GB + c * 6 + 3, agg1[2], agg1[3], ai);
      PHASE(GB + c * 6 + 4, ldsA(A1l, arow, 0, kg), ldsA(A1l, arow, 32, kg), ah);
      PHASE(GB + c * 6 + 5, ldsA(A1l, arow, 64, kg), ldsA(A1l, arow, 96, kg), ah);
    }
    if (c < 2) {
#pragma unroll
      for (int tn = 0; tn < 8; ++tn) {
        int col = tn * 16 + ml;
        float cbc = cb[128 + c * 128 + col];
#pragma unroll
        for (int e = 0; e < 4; ++e) {
          float v = sigm(ai[tn][e] + ah[tn][e] + cbc);
          if (c == 0) rr[tn][e] = v;
          else zz[tn][e] = v;
        }
      }
    } else {
#pragma unroll
      for (int tn = 0; tn < 8; ++tn) {
        int col = tn * 16 + ml;
        float cbn = cb[384 + col];
        float bh = bhh[256 + col];
#pragma unroll
        for (int e = 0; e < 4; ++e) {
          int lrow = 16 * w + kg * 4 + e;
          float x = (ai[tn][e] + cbn) + rr[tn][e] * (ah[tn][e] + bh);
          x = fminf(fmaxf(x, -15.f), 15.f);
          float ex = __expf(2.f * x);
          float nv = (ex - 1.f) / (ex + 1.f);
          float fu = bf2f(A1l[XLI(lrow, col)]);
          float ht = fmaf(zz[tn][e], fu - nv, nv);
          ht = fmaxf(ht, 0.f);
          int node = base + lrow;
          if (node < n) OUT[(size_t)node * 128 + col] = ht;
        }
      }
    }
  }
}

extern "C" void kernel_launch(void* const* d_in, const int* in_sizes, int n_in,
                              void* d_out, int out_size, void* d_ws, size_t ws_size,
                              hipStream_t stream) {
  const float* h1_course = (const float*)d_in[3];
  const float* h1_object = (const float*)d_in[4];
  const float* h1_enroll = (const float*)d_in[5];
  const float* h2_course = (const float*)d_in[6];
  const float* h2_object = (const float*)d_in[7];
  const float* h2_enroll = (const float*)d_in[8];
  const float* h_course = (const float*)d_in[0];
  const float* h_object = (const float*)d_in[1];
  const float* h_enroll = (const float*)d_in[2];
  const int* src_co = (const int*)d_in[9];
  const int* dst_co = (const int*)d_in[10];
  const int* src_oc = (const int*)d_in[11];
  const int* dst_oc = (const int*)d_in[12];
  const int* src_eo = (const int*)d_in[13];
  const int* dst_eo = (const int*)d_in[14];
  const int* src_oe = (const int*)d_in[15];
  const int* dst_oe = (const int*)d_in[16];
  const float* W_co = (const float*)d_in[17];
  const float* b_co = (const float*)d_in[18];
  const float* W_oc = (const float*)d_in[19];
  const float* b_oc = (const float*)d_in[20];
  const float* W_eo = (const float*)d_in[21];
  const float* b_eo = (const float*)d_in[22];
  const float* W_oe = (const float*)d_in[23];
  const float* b_oe = (const float*)d_in[24];
  const float* gate_W = (const float*)d_in[25];
  const float* gate_b = (const float*)d_in[26];
  const float* W_ih = (const float*)d_in[27];
  const float* W_hh = (const float*)d_in[28];
  const float* b_ih = (const float*)d_in[29];
  const float* b_hh = (const float*)d_in[30];

  float* out = (float*)d_out;
  float* out_c = out;
  float* out_o = out + (size_t)NCn * 128;
  float* out_e = out + (size_t)(NCn + NOn) * 128;
  float* g_c = out + (size_t)(NCn + NOn + NEn) * 128;
  float* g_o = g_c + (size_t)NCn * 128;
  float* g_e = g_o + (size_t)NOn * 128;

  // ws layout (assumes ws_size >= ~9.4 MB)
  char* wsb = (char*)d_ws;
  int* CNT_DST = (int*)(wsb + 0);            // 402000
  int* CNT_SRC = (int*)(wsb + 1608000);      // 402000
  int* OFF = (int*)(wsb + 3216000);          // 402000
  int* SRCS = (int*)(wsb + 4824000);         // 600000
  int* BSUM = (int*)(wsb + 7224000);         // 1600
  int* BEXC = (int*)(wsb + 7230400);         // 1600
  float* P = (float*)(wsb + 7236800);        // 262144
  float* CBv = (float*)(wsb + 8285376);      // 1536
  unsigned short* STRM = (unsigned short*)(wsb + 8291520);  // 507904

  hipMemsetAsync(CNT_DST, 0, 804000 * sizeof(int), stream);

  count2<<<(ECOn + 255) / 256, 256, 0, stream>>>(src_co, dst_co, ECOn, CNT_SRC + 0, CNT_DST + 0);
  count2<<<(EOCn + 255) / 256, 256, 0, stream>>>(src_oc, dst_oc, EOCn, CNT_SRC + 2000, CNT_DST + 100000);
  count2<<<(EEOn + 255) / 256, 256, 0, stream>>>(src_eo, dst_eo, EEOn, CNT_SRC + 102000, CNT_DST + 102000);
  count2<<<(EOEn + 255) / 256, 256, 0, stream>>>(src_oe, dst_oe, EOEn, CNT_SRC + 302000, CNT_DST + 202000);

  scan1<<<NB1, 256, 0, stream>>>(CNT_DST, OFF, BSUM, NDST);
  scan2<<<1, 256, 0, stream>>>(BSUM, BEXC, NB1);
  scan3<<<NB1, 256, 0, stream>>>(OFF, BEXC, NDST);

  fillk<<<(ECOn + 255) / 256, 256, 0, stream>>>(src_co, dst_co, ECOn, OFF + 0, SRCS);
  fillk<<<(EOCn + 255) / 256, 256, 0, stream>>>(src_oc, dst_oc, EOCn, OFF + 100000, SRCS);
  fillk<<<(EEOn + 255) / 256, 256, 0, stream>>>(src_eo, dst_eo, EEOn, OFF + 102000, SRCS);
  fillk<<<(EOEn + 255) / 256, 256, 0, stream>>>(src_oe, dst_oe, EOEn, OFF + 202000, SRCS);

  wgemmP<<<1024, 256, 0, stream>>>(W_co, W_oc, W_eo, W_oe, gate_W, W_ih, P);
  cbias<<<6, 256, 0, stream>>>(gate_W, W_ih, gate_b, b_ih, b_hh, b_co, b_oc, b_eo, b_oe, CBv);
  packk<<<248, 256, 0, stream>>>(P, gate_W, W_hh, STRM);

  // enroll (rel oe: dst seg 202000, src seg 302000, Hsrc = h_object)
  fuse_kernel<1><<<(NEn + 127) / 128, 512, 0, stream>>>(
      h1_enroll, h2_enroll, h_object, CNT_DST + 202000, OFF + 202000, CNT_SRC + 302000,
      nullptr, nullptr, nullptr, nullptr, SRCS, STRM + (size_t)44 * 8192, CBv + 1024, b_hh,
      out_e, g_e, NEn);
  // object (rel co: dst 0, src 0 (h_course); rel eo: dst 102000, src 102000 (h_enroll))
  fuse_kernel<2><<<(NOn + 127) / 128, 512, 0, stream>>>(
      h1_object, h2_object, h_course, CNT_DST + 0, OFF + 0, CNT_SRC + 0,
      h_enroll, CNT_DST + 102000, OFF + 102000, CNT_SRC + 102000, SRCS,
      STRM + (size_t)18 * 8192, CBv + 512, b_hh, out_o, g_o, NOn);
  // course (rel oc: dst seg 100000, src seg 2000, Hsrc = h_object)
  fuse_kernel<1><<<(NCn + 127) / 128, 512, 0, stream>>>(
      h1_course, h2_course, h_object, CNT_DST + 100000, OFF + 100000, CNT_SRC + 2000,
      nullptr, nullptr, nullptr, nullptr, SRCS, STRM + 0, CBv + 0, b_hh,
      out_c, g_c, NCn);
}